// Round 7
// baseline (778.315 us; speedup 1.0000x reference)
//
#include <hip/hip_runtime.h>
#include <hip/hip_cooperative_groups.h>

namespace cg = cooperative_groups;

// B=256 queries, D=2048, d=64 hash dim, N=100000 database, C=100 classes,
// K=1000 SMALLEST-sim selection. Inputs f32, labels int, output f32.
//
// Exact-set algorithm (absmax 0 in R2..R6): MFMA f16 screening GEMM with a
// rigorous error bound M vs f64 truth (|v64 - stored_f16_score| <= M =
// 0.5*S*1.1e-3 + (50+0.55S)*2^-10 + 0.05, S = ||out_b||*max||c||, by
// Cauchy-Schwarz over f16-cvt + f32-accum + f16-store errors):
//   score <  TL = lo_tb - 2M  => certainly in f64 top-K  (label-counted)
//   score >  TH = hi_tb + 2M  => certainly out
//   else                      => candidate (~370/row), exact f64 resolve.
//
// R7: ONE cooperative launch (R6: ~100 us of the 200 was ~10us/dispatch
// launch overhead across 9 enqueues). Phases split by grid.sync():
//   p0 prep   : codes f32->f16 + per-block max||c||^2 slots + detect labels
//               dtype + out=x@W (f64+f16) + ||out||^2 + zero belowCnt
//   p1 mhist  : MFMA screen -> f16 score store + per-(chunk,row) u16 hist slab
//   p2 scan   : sum slabs -> threshold bucket -> [TL,TH] per row
//   p3 class  : stream scores: below -> LDS label hist; band -> candidates
//   p4 final  : gather, exact f64 sims, bitonic sort, emit probs
// Fallback: same phases as 5 plain kernels if cooperative enqueue fails.

#define GRID 1024
#define TPB 256
#define NBK 256          // buckets per row histogram
#define NCHX 128         // code-chunks for the MFMA pass (grid = NCHX * B/MROWS)
#define MROWS 32         // out-rows per MFMA block (two 16-row tiles)
#define NCCH 4           // row-chunks for classify (grid = NCCH * B)
#define CAPB 512         // per-(chunk,row) candidate capacity (expected ~92)
#define CAPC 1024        // per-row candidate capacity (expected ~370)
#define NCLS 100

typedef _Float16 half8 __attribute__((ext_vector_type(8)));
typedef float floatx4 __attribute__((ext_vector_type(4)));

struct Ptrs {
  const float* x; const float* W; const float* codes;
  const int* labels; const int* Kp;
  double* out64; unsigned short* out16; double* B1sq;
  float2* rowTH; int* shiftp; float* pmax;
  unsigned* belowCnt; unsigned* ccnt; unsigned* cand;
  unsigned short* histg; unsigned short* codes16; unsigned short* simh;
  float* outp;
  int B, N, D, Npad, nCvt, cpb;
};

union SMem {
  struct { float red[TPB]; int flag; } p0c;
  struct { double red[TPB]; } p0o;
  struct { unsigned hist[MROWS * NBK]; float sP[MROWS]; float sQ[MROWS]; float r[TPB]; } p1;
  struct { unsigned s[NBK]; float r[TPB]; } p2;
  struct { unsigned lab[NCLS]; unsigned cnt; } p3;
  struct { double key[CAPC]; int kidx[CAPC]; unsigned lab[NCLS]; int soff[NCCH + 1]; unsigned btot; } p4;
};

static __device__ __forceinline__ unsigned short f2h(float v) {
  _Float16 h = (_Float16)v; unsigned short u; __builtin_memcpy(&u, &h, 2); return u;
}
static __device__ __forceinline__ float h2f(unsigned short u) {
  _Float16 h; __builtin_memcpy(&h, &u, 2); return (float)h;
}
static __device__ __forceinline__ unsigned packh2(float a, float b) {
  return (unsigned)f2h(a) | ((unsigned)f2h(b) << 16);
}

// shared range math; 1-ulp discrepancies absorbed by the 2M margins
static __device__ __forceinline__ void rowRange(double b1sq, double cmax,
                                                double& lo, double& inv, double& bw) {
  double hr = 0.5 * sqrt(b1sq * cmax) * 1.000001 + 9.0;  // +9 >> M
  lo = 50.0 - hr;
  bw = (2.0 * hr) / (double)NBK;
  inv = (double)NBK / (2.0 * hr);
}

// exact f64 dot for candidate resolution (order-stable chain)
static __device__ __forceinline__ double dot1(const float* __restrict__ codes, int n,
                                              const double* __restrict__ od) {
  const float4* crow = (const float4*)(codes + (size_t)n * 64);
  double a = 0.0;
#pragma unroll
  for (int i = 0; i < 16; ++i) {
    float4 q = crow[i];
    a = fma((double)q.x, od[i*4+0], a);
    a = fma((double)q.y, od[i*4+1], a);
    a = fma((double)q.z, od[i*4+2], a);
    a = fma((double)q.w, od[i*4+3], a);
  }
  return a;
}

// all-threads block max-reduce of the 1024 per-block pmax slots
static __device__ __forceinline__ float reduce_cmax(const float* __restrict__ pmax,
                                                    float* scratch) {
  int tid = threadIdx.x;
  float m = fmaxf(fmaxf(pmax[tid], pmax[tid + 256]),
                  fmaxf(pmax[tid + 512], pmax[tid + 768]));
  scratch[tid] = m; __syncthreads();
  for (int off = 128; off > 0; off >>= 1) {
    if (tid < off) scratch[tid] = fmaxf(scratch[tid], scratch[tid + off]);
    __syncthreads();
  }
  float r = scratch[0];
  __syncthreads();
  return r;
}

// MFMA A-fragment loader (mfma_f32_16x16x32_f16, m89-verified family):
//   A: lane holds A[m=lane&15][k=(lane>>4)*8+j]; D: reg r = D[(lane>>4)*4+r][lane&15]
static __device__ __forceinline__ void loadA(const unsigned short* __restrict__ out16,
                                             int m0, int mr, int quad,
                                             half8& a00, half8& a01, half8& a10, half8& a11) {
  const uint4* o4 = (const uint4*)out16;
  uint4 u;
  u = o4[(size_t)(m0 + mr) * 8 + quad];          __builtin_memcpy(&a00, &u, 16);
  u = o4[(size_t)(m0 + mr) * 8 + 4 + quad];      __builtin_memcpy(&a01, &u, 16);
  u = o4[(size_t)(m0 + 16 + mr) * 8 + quad];     __builtin_memcpy(&a10, &u, 16);
  u = o4[(size_t)(m0 + 16 + mr) * 8 + 4 + quad]; __builtin_memcpy(&a11, &u, 16);
}

// ================= phase 0: prep =================
static __device__ void phase0(const Ptrs& P, SMem& sm) {
  int bid = blockIdx.x, tid = threadIdx.x;
  for (int i = bid * TPB + tid; i < P.B * NCLS; i += GRID * TPB) P.belowCnt[i] = 0u;

  if (bid < P.nCvt) {                       // codes convert + norm (+detect in blk 0)
    if (bid == 0) {
      if (tid == 0) sm.p0c.flag = 0;
      __syncthreads();
      int mm = P.N < 256 ? P.N : 256;
      if (tid < mm && P.labels[2 * tid + 1] != 0) atomicOr(&sm.p0c.flag, 1);
      __syncthreads();
      if (tid == 0) *P.shiftp = sm.p0c.flag ? 0 : 1;  // label(n)=labels[n<<shift]
      __syncthreads();
    }
    float m = 0.0f;
    int n = bid * TPB + tid;
    if (n < P.N) {
      const float4* crow = (const float4*)(P.codes + (size_t)n * 64);
      uint4* orow = (uint4*)(P.codes16 + (size_t)n * 64);
      double c2 = 0.0;
#pragma unroll
      for (int i = 0; i < 8; ++i) {
        float4 qa = crow[2*i], qb = crow[2*i+1];
        c2 = fma((double)qa.x,(double)qa.x,c2); c2 = fma((double)qa.y,(double)qa.y,c2);
        c2 = fma((double)qa.z,(double)qa.z,c2); c2 = fma((double)qa.w,(double)qa.w,c2);
        c2 = fma((double)qb.x,(double)qb.x,c2); c2 = fma((double)qb.y,(double)qb.y,c2);
        c2 = fma((double)qb.z,(double)qb.z,c2); c2 = fma((double)qb.w,(double)qb.w,c2);
        uint4 o;
        o.x = packh2(qa.x, qa.y); o.y = packh2(qa.z, qa.w);
        o.z = packh2(qb.x, qb.y); o.w = packh2(qb.z, qb.w);
        orow[i] = o;
      }
      m = (float)(c2 * 1.000001);
    } else if (n < P.Npad) {
      uint4* orow = (uint4*)(P.codes16 + (size_t)n * 64);
      uint4 z = {0u,0u,0u,0u};
#pragma unroll
      for (int i = 0; i < 8; ++i) orow[i] = z;
    }
    sm.p0c.red[tid] = m; __syncthreads();
    for (int off = 128; off > 0; off >>= 1) {
      if (tid < off) sm.p0c.red[tid] = fmaxf(sm.p0c.red[tid], sm.p0c.red[tid + off]);
      __syncthreads();
    }
    if (tid == 0) P.pmax[bid] = sm.p0c.red[0];
  } else if (bid >= 512 && bid < 512 + P.B) {   // out = x@W row (f64 + f16)
    if (tid == 0) P.pmax[bid] = 0.0f;
    int b = bid - 512;
    int t = tid & 63, w = tid >> 6;       // 4 K-chunks x 8 accumulators
    int kc = P.D >> 2;
    const float* xr = P.x + (size_t)b * P.D;
    double a[8];
#pragma unroll
    for (int j = 0; j < 8; ++j) a[j] = 0.0;
    for (int k = w * kc; k < (w + 1) * kc; k += 8) {
      float4 xv0 = *(const float4*)(xr + k);
      float4 xv1 = *(const float4*)(xr + k + 4);
      float xs[8] = {xv0.x, xv0.y, xv0.z, xv0.w, xv1.x, xv1.y, xv1.z, xv1.w};
#pragma unroll
      for (int j = 0; j < 8; ++j)
        a[j] = fma((double)xs[j], (double)P.W[(size_t)(k + j) * 64 + t], a[j]);
    }
    sm.p0o.red[tid] = ((a[0]+a[1])+(a[2]+a[3])) + ((a[4]+a[5])+(a[6]+a[7]));
    __syncthreads();
    double o = 0.0;
    if (w == 0) {
      o = sm.p0o.red[t] + sm.p0o.red[64+t] + sm.p0o.red[128+t] + sm.p0o.red[192+t];
      P.out64[(size_t)b * 64 + t] = o;
      P.out16[(size_t)b * 64 + t] = f2h((float)o);
    }
    __syncthreads();
    if (w == 0) sm.p0o.red[t] = o * o;
    __syncthreads();
    if (tid == 0) {
      double s = 0.0;
      for (int i = 0; i < 64; ++i) s += sm.p0o.red[i];
      P.B1sq[b] = s;
    }
  } else {
    if (tid == 0) P.pmax[bid] = 0.0f;
  }
}

// ================= phase 1: MFMA screen -> score store + hist slabs =================
static __device__ void phase1(const Ptrs& P, SMem& sm) {
  int tid = threadIdx.x, bid = blockIdx.x;
  int cx = bid & (NCHX - 1), m0 = (bid >> 7) * MROWS;
  float cmax = reduce_cmax(P.pmax, sm.p1.r);
  for (int i = tid; i < MROWS * NBK; i += TPB) sm.p1.hist[i] = 0u;
  if (tid < MROWS) {
    double lo, inv, bw;
    rowRange(P.B1sq[m0 + tid], (double)cmax, lo, inv, bw);
    sm.p1.sP[tid] = (float)(-0.5 * inv);   // bucket = trunc(d*P + Q), monotone in v
    sm.p1.sQ[tid] = (float)((50.0 - lo) * inv);
  }
  __syncthreads();
  int l = tid & 63, w = tid >> 6, quad = l >> 4, mr = l & 15;
  half8 a00, a01, a10, a11;
  loadA(P.out16, m0, mr, quad, a00, a01, a10, a11);
  float Pv0[4], Qv0[4], Pv1[4], Qv1[4];
#pragma unroll
  for (int r = 0; r < 4; ++r) {
    Pv0[r] = sm.p1.sP[quad*4 + r];      Qv0[r] = sm.p1.sQ[quad*4 + r];
    Pv1[r] = sm.p1.sP[16 + quad*4 + r]; Qv1[r] = sm.p1.sQ[16 + quad*4 + r];
  }
  int cstart = cx * P.cpb;
  int cend = cstart + P.cpb; if (cend > P.N) cend = P.N;
  const uint4* c4 = (const uint4*)P.codes16;
  floatx4 z = {0.f, 0.f, 0.f, 0.f};
  for (int base = cstart; base < cend; base += 64) {
    int nrow = base + w * 16 + mr;
    int nc = nrow < P.Npad ? nrow : P.Npad - 1;
    uint4 ub0 = c4[(size_t)nc * 8 + quad];
    uint4 ub1 = c4[(size_t)nc * 8 + 4 + quad];
    half8 b0, b1;
    __builtin_memcpy(&b0, &ub0, 16); __builtin_memcpy(&b1, &ub1, 16);
    floatx4 d0 = __builtin_amdgcn_mfma_f32_16x16x32_f16(a00, b0, z, 0, 0, 0);
    d0 = __builtin_amdgcn_mfma_f32_16x16x32_f16(a01, b1, d0, 0, 0, 0);
    floatx4 d1 = __builtin_amdgcn_mfma_f32_16x16x32_f16(a10, b0, z, 0, 0, 0);
    d1 = __builtin_amdgcn_mfma_f32_16x16x32_f16(a11, b1, d1, 0, 0, 0);
    if (nrow < P.N) {
#pragma unroll
      for (int r = 0; r < 4; ++r) {
        float v0 = fmaf(d0[r], -0.5f, 50.0f);
        P.simh[(size_t)(m0 + quad*4 + r) * P.N + nrow] = f2h(v0);
        int bk0 = (int)fmaf(d0[r], Pv0[r], Qv0[r]);
        bk0 = bk0 < 0 ? 0 : (bk0 > NBK-1 ? NBK-1 : bk0);
        atomicAdd(&sm.p1.hist[(quad*4 + r) * NBK + bk0], 1u);
        float v1 = fmaf(d1[r], -0.5f, 50.0f);
        P.simh[(size_t)(m0 + 16 + quad*4 + r) * P.N + nrow] = f2h(v1);
        int bk1 = (int)fmaf(d1[r], Pv1[r], Qv1[r]);
        bk1 = bk1 < 0 ? 0 : (bk1 > NBK-1 ? NBK-1 : bk1);
        atomicAdd(&sm.p1.hist[(16 + quad*4 + r) * NBK + bk1], 1u);
      }
    }
  }
  __syncthreads();
  for (int i = tid; i < MROWS * NBK; i += TPB)   // exclusive u16 slab, plain stores
    P.histg[((size_t)cx * P.B + (m0 + (i >> 8))) * NBK + (i & (NBK - 1))] =
        (unsigned short)sm.p1.hist[i];
}

// ================= phase 2: slab sum + scan -> [TL,TH] =================
static __device__ void phase2(const Ptrs& P, SMem& sm) {
  int b = blockIdx.x, tid = threadIdx.x;
  if (b >= P.B) return;
  float cmax = reduce_cmax(P.pmax, sm.p2.r);
  unsigned acc = 0;
  for (int cx = 0; cx < NCHX; ++cx)
    acc += P.histg[((size_t)cx * P.B + b) * NBK + tid];   // coalesced u16
  sm.p2.s[tid] = acc;
  __syncthreads();
  for (int off = 1; off < NBK; off <<= 1) {
    unsigned add = (tid >= off) ? sm.p2.s[tid - off] : 0u;
    __syncthreads();
    sm.p2.s[tid] += add;
    __syncthreads();
  }
  unsigned K = (unsigned)P.Kp[0];
  unsigned cum = sm.p2.s[tid], prev = tid ? sm.p2.s[tid - 1] : 0u;
  if (cum >= K && prev < K) {              // exactly one thread: tb = tid
    double lo, inv, bw;
    rowRange(P.B1sq[b], (double)cmax, lo, inv, bw);
    double S = sqrt(P.B1sq[b] * (double)cmax);
    // M: f16 input cvt + f32 accum + f16 STORE quantization (2x slack each)
    double M = 0.5 * S * 1.1e-3 + (50.0 + 0.55 * S) * 0x1p-10 + 0.05;
    double lot = lo + (double)tid * bw;
    P.rowTH[b] = make_float2((float)(lot - 2.0 * M - 1e-3),
                             (float)(lot + bw + 2.0 * M + 1e-3));
  }
}

// ================= phase 3: stream scores -> below hist / candidates =================
static __device__ void phase3(const Ptrs& P, SMem& sm) {
  int tid = threadIdx.x, bid = blockIdx.x;
  int b = bid >> 2, ch = bid & (NCCH - 1);
  if (b >= P.B) return;
  for (int i = tid; i < NCLS; i += TPB) sm.p3.lab[i] = 0u;
  if (tid == 0) sm.p3.cnt = 0u;
  __syncthreads();
  float2 th = P.rowTH[b];
  float TL = th.x, TH = th.y;
  int shift = *P.shiftp;
  const unsigned short* rp = P.simh + (size_t)b * P.N;
  const uint4* rp4 = (const uint4*)rp;
  int nu4 = P.N >> 3;
  int q = (nu4 + NCCH - 1) / NCCH;
  int i0 = ch * q, i1 = i0 + q; if (i1 > nu4) i1 = nu4;
  unsigned* seg = P.cand + ((size_t)ch * P.B + b) * CAPB;
  for (int i = i0 + tid; i < i1; i += TPB) {
    uint4 u = rp4[i];
    unsigned uu[4] = {u.x, u.y, u.z, u.w};
#pragma unroll
    for (int k = 0; k < 8; ++k) {
      unsigned short us = (unsigned short)((uu[k >> 1] >> ((k & 1) * 16)) & 0xFFFFu);
      float hv = h2f(us);
      if (hv < TL) {                       // certain in top-K (~1%)
        atomicAdd(&sm.p3.lab[P.labels[(size_t)(i*8 + k) << shift]], 1u);
      } else if (hv <= TH) {               // band (~0.4%)
        unsigned pos = atomicAdd(&sm.p3.cnt, 1u);
        if (pos < CAPB) seg[pos] = (unsigned)(i*8 + k);
      }
    }
  }
  if (ch == NCCH - 1) {                    // N%8 tail
    for (int n = (nu4 << 3) + tid; n < P.N; n += TPB) {
      float hv = h2f(rp[n]);
      if (hv < TL) {
        atomicAdd(&sm.p3.lab[P.labels[(size_t)n << shift]], 1u);
      } else if (hv <= TH) {
        unsigned pos = atomicAdd(&sm.p3.cnt, 1u);
        if (pos < CAPB) seg[pos] = (unsigned)n;
      }
    }
  }
  __syncthreads();
  if (tid == 0) {
    unsigned c = sm.p3.cnt;
    P.ccnt[(size_t)ch * P.B + b] = c < CAPB ? c : CAPB;   // plain store
  }
  for (int i = tid; i < NCLS; i += TPB) {  // fire-and-forget merge
    unsigned c = sm.p3.lab[i];
    if (c) atomicAdd(&P.belowCnt[b * NCLS + i], c);
  }
}

// ================= phase 4: exact f64 resolve + emit =================
static __device__ void phase4(const Ptrs& P, SMem& sm) {
  int b = blockIdx.x, tid = threadIdx.x;
  if (b >= P.B) return;
  if (tid == 0) {
    sm.p4.btot = 0u;
    sm.p4.soff[0] = 0;
    for (int s = 0; s < NCCH; ++s) {
      int nx = sm.p4.soff[s] + (int)P.ccnt[(size_t)s * P.B + b];
      sm.p4.soff[s + 1] = nx < CAPC ? nx : CAPC;
    }
  }
  __syncthreads();
  for (int c = tid; c < NCLS; c += TPB) {
    unsigned v = P.belowCnt[b * NCLS + c];
    if (v) atomicAdd(&sm.p4.btot, v);
  }
  for (int s = 0; s < NCCH; ++s) {
    int c0 = sm.p4.soff[s], len = sm.p4.soff[s + 1] - c0;
    const unsigned* seg = P.cand + ((size_t)s * P.B + b) * CAPB;
    for (int j = tid; j < len; j += TPB) sm.p4.kidx[c0 + j] = (int)seg[j];
  }
  __syncthreads();
  int cnt = sm.p4.soff[NCCH];
  int K = P.Kp[0];
  int need = K - (int)sm.p4.btot;
  int M = 1; while (M < cnt) M <<= 1;
  const double* od = P.out64 + (size_t)b * 64;
  for (int i = tid; i < M; i += TPB) {
    if (i < cnt) {
      sm.p4.key[i] = fma(dot1(P.codes, sm.p4.kidx[i], od), -0.5, 50.0);
    } else { sm.p4.key[i] = __builtin_inf(); sm.p4.kidx[i] = 0x7FFFFFFF; }
  }
  __syncthreads();
  for (int size = 2; size <= M; size <<= 1) {
    for (int stride = size >> 1; stride > 0; stride >>= 1) {
      for (int i = tid; i < M; i += TPB) {
        int j = i ^ stride;
        if (j > i) {
          double ki = sm.p4.key[i], kj = sm.p4.key[j];
          int ii = sm.p4.kidx[i], ij = sm.p4.kidx[j];
          bool up = ((i & size) == 0);
          bool sw = up ? (kj < ki || (kj == ki && ij < ii))
                       : (kj > ki || (kj == ki && ij > ii));
          if (sw) { sm.p4.key[i] = kj; sm.p4.key[j] = ki;
                    sm.p4.kidx[i] = ij; sm.p4.kidx[j] = ii; }
        }
      }
      __syncthreads();
    }
  }
  for (int i = tid; i < NCLS; i += TPB) sm.p4.lab[i] = 0u;
  __syncthreads();
  int shift = *P.shiftp;
  int take = need < cnt ? need : cnt;
  if (take < 0) take = 0;
  for (int i = tid; i < take; i += TPB)
    atomicAdd(&sm.p4.lab[P.labels[(size_t)sm.p4.kidx[i] << shift]], 1u);
  __syncthreads();
  double Kd = (double)K;
  for (int c = tid; c < NCLS; c += TPB)
    P.outp[b * NCLS + c] = (float)((double)(P.belowCnt[b * NCLS + c] + sm.p4.lab[c]) / Kd);
}

// ---- cooperative mega-kernel ----
__global__ __launch_bounds__(TPB, 4) void mega(Ptrs P) {
  cg::grid_group g = cg::this_grid();
  __shared__ SMem sm;
  phase0(P, sm); g.sync();
  phase1(P, sm); g.sync();
  phase2(P, sm); g.sync();
  phase3(P, sm); g.sync();
  phase4(P, sm);
}

// ---- fallback: phases as plain kernels (kernel boundary = device sync) ----
__global__ __launch_bounds__(TPB, 4) void kp0(Ptrs P) { __shared__ SMem sm; phase0(P, sm); }
__global__ __launch_bounds__(TPB, 4) void kp1(Ptrs P) { __shared__ SMem sm; phase1(P, sm); }
__global__ __launch_bounds__(TPB, 4) void kp2(Ptrs P) { __shared__ SMem sm; phase2(P, sm); }
__global__ __launch_bounds__(TPB, 4) void kp3(Ptrs P) { __shared__ SMem sm; phase3(P, sm); }
__global__ __launch_bounds__(TPB, 4) void kp4(Ptrs P) { __shared__ SMem sm; phase4(P, sm); }

extern "C" void kernel_launch(void* const* d_in, const int* in_sizes, int n_in,
                              void* d_out, int out_size, void* d_ws, size_t ws_size,
                              hipStream_t stream) {
  Ptrs P;
  P.x      = (const float*)d_in[0];
  P.W      = (const float*)d_in[1];
  P.codes  = (const float*)d_in[2];
  P.labels = (const int*)d_in[3];
  P.Kp     = (const int*)d_in[4];
  P.B    = out_size / NCLS;                 // 256
  P.N    = in_sizes[3];                     // 100000
  P.D    = in_sizes[0] / P.B;               // 2048
  P.Npad = (P.N + 255) & ~255;              // 100096
  P.nCvt = P.Npad / 256;                    // 391
  P.cpb  = (((P.Npad + NCHX - 1) / NCHX) + 63) & ~63;  // 832
  P.outp = (float*)d_out;

  char* p = (char*)d_ws;
  P.out64    = (double*)p;         p += (size_t)P.B * 64 * sizeof(double);        // 128 KB
  P.out16    = (unsigned short*)p; p += (size_t)P.B * 64 * 2;                     // 32 KB
  P.B1sq     = (double*)p;         p += (size_t)P.B * sizeof(double);             // 2 KB
  P.rowTH    = (float2*)p;         p += (size_t)P.B * sizeof(float2);             // 2 KB
  P.shiftp   = (int*)p;            p += 64;
  P.pmax     = (float*)p;          p += (size_t)GRID * sizeof(float);             // 4 KB
  P.belowCnt = (unsigned*)p;       p += (size_t)P.B * NCLS * sizeof(unsigned);    // 100 KB
  P.ccnt     = (unsigned*)p;       p += (size_t)NCCH * P.B * sizeof(unsigned);    // 4 KB
  P.cand     = (unsigned*)p;       p += (size_t)NCCH * P.B * CAPB * sizeof(unsigned); // 2 MB
  P.histg    = (unsigned short*)p; p += (size_t)NCHX * P.B * NBK * 2;             // 16 MB
  P.codes16  = (unsigned short*)p; p += (size_t)P.Npad * 64 * 2;                  // 12.8 MB
  P.simh     = (unsigned short*)p;                                                // 51.2 MB

  void* args[] = { (void*)&P };
  if (hipLaunchCooperativeKernel((const void*)mega, dim3(GRID), dim3(TPB),
                                 args, 0, stream) != hipSuccess) {
    kp0<<<GRID, TPB, 0, stream>>>(P);
    kp1<<<GRID, TPB, 0, stream>>>(P);
    kp2<<<GRID, TPB, 0, stream>>>(P);
    kp3<<<GRID, TPB, 0, stream>>>(P);
    kp4<<<GRID, TPB, 0, stream>>>(P);
  }
}

// Round 8
// 307.470 us; speedup vs baseline: 2.5314x; 2.5314x over previous
//
#include <hip/hip_runtime.h>

// B=256 queries, D=2048, d=64 hash dim, N=100000 database, C=100 classes,
// K=1000 SMALLEST-sim selection. Inputs f32, labels int, output f32.
//
// Exact-set algorithm (absmax 0 in R2..R7): MFMA f16 screening GEMM with
// rigorous error bound M vs f64 truth (|v64 - score| <= M, Cauchy-Schwarz
// over f16-cvt + f32-accum + f16-store errors):
//   score < TL = lo_tb - 2M  => certainly in f64 top-K  (label-counted)
//   score > TH = hi_tb + 2M  => certainly out
//   else                     => candidate (~370/row), exact f64 resolve.
//
// R8: R7's validated phases as 4 PLAIN kernels (grid.sync cost ~150us each;
// kernel boundaries do the same flush, HW-optimized):
//   k_prep      : detect + codes f32->f16 + pmax slots + out=x@W + zero state
//   k_gemmhist  : MFMA screen -> f16 score store + per-(chunk,row) u16 hist
//   k_scan      : sum slabs -> threshold bucket -> [TL,TH] per row
//   k_classfinal: stream scores -> below-hist/candidates; LAST chunk-block of
//                 each row (device-fenced done-counter) runs exact f64 resolve.

#define TPB 256
#define NBK 256          // buckets per row histogram
#define NCHX 128         // code-chunks in gemmhist (grid.x)
#define MROWS 32         // out-rows per gemmhist block
#define NCCH 4           // row-chunks in classfinal
#define CAPB 512         // per-(chunk,row) candidate capacity (expected ~92)
#define CAPC 1024        // per-row candidate capacity (expected ~370)
#define NCLS 100

typedef _Float16 half8 __attribute__((ext_vector_type(8)));
typedef float floatx4 __attribute__((ext_vector_type(4)));

struct Ptrs {
  const float* x; const float* W; const float* codes;
  const int* labels; const int* Kp;
  double* out64; double* B1sq; unsigned short* out16;
  float2* rowTH; int* shiftp; float* pmax;
  unsigned* belowCnt; unsigned* ccnt; unsigned* cand; unsigned* rowdone;
  unsigned short* histg; unsigned short* codes16; unsigned short* simh;
  float* outp;
  int B, N, D, Npad, nCvt, gridPrep, cpb;
};

static __device__ __forceinline__ unsigned short f2h(float v) {
  _Float16 h = (_Float16)v; unsigned short u; __builtin_memcpy(&u, &h, 2); return u;
}
static __device__ __forceinline__ float h2f(unsigned short u) {
  _Float16 h; __builtin_memcpy(&h, &u, 2); return (float)h;
}
static __device__ __forceinline__ unsigned packh2(float a, float b) {
  return (unsigned)f2h(a) | ((unsigned)f2h(b) << 16);
}

static __device__ __forceinline__ void rowRange(double b1sq, double cmax,
                                                double& lo, double& inv, double& bw) {
  double hr = 0.5 * sqrt(b1sq * cmax) * 1.000001 + 9.0;  // +9 >> M
  lo = 50.0 - hr;
  bw = (2.0 * hr) / (double)NBK;
  inv = (double)NBK / (2.0 * hr);
}

static __device__ __forceinline__ double dot1(const float* __restrict__ codes, int n,
                                              const double* __restrict__ od) {
  const float4* crow = (const float4*)(codes + (size_t)n * 64);
  double a = 0.0;
#pragma unroll
  for (int i = 0; i < 16; ++i) {
    float4 q = crow[i];
    a = fma((double)q.x, od[i*4+0], a);
    a = fma((double)q.y, od[i*4+1], a);
    a = fma((double)q.z, od[i*4+2], a);
    a = fma((double)q.w, od[i*4+3], a);
  }
  return a;
}

static __device__ __forceinline__ float reduce_cmax(const float* __restrict__ pmax,
                                                    int n, float* scratch) {
  int tid = threadIdx.x;
  float m = 0.0f;
  for (int i = tid; i < n; i += TPB) m = fmaxf(m, pmax[i]);
  scratch[tid] = m; __syncthreads();
  for (int off = 128; off > 0; off >>= 1) {
    if (tid < off) scratch[tid] = fmaxf(scratch[tid], scratch[tid + off]);
    __syncthreads();
  }
  float r = scratch[0];
  __syncthreads();
  return r;
}

// MFMA A-fragment loader (mfma_f32_16x16x32_f16, m89-verified family):
//   A: lane holds A[m=lane&15][k=(lane>>4)*8+j]; D: reg r = D[(lane>>4)*4+r][lane&15]
static __device__ __forceinline__ void loadA(const unsigned short* __restrict__ out16,
                                             int m0, int mr, int quad,
                                             half8& a00, half8& a01, half8& a10, half8& a11) {
  const uint4* o4 = (const uint4*)out16;
  uint4 u;
  u = o4[(size_t)(m0 + mr) * 8 + quad];          __builtin_memcpy(&a00, &u, 16);
  u = o4[(size_t)(m0 + mr) * 8 + 4 + quad];      __builtin_memcpy(&a01, &u, 16);
  u = o4[(size_t)(m0 + 16 + mr) * 8 + quad];     __builtin_memcpy(&a10, &u, 16);
  u = o4[(size_t)(m0 + 16 + mr) * 8 + 4 + quad]; __builtin_memcpy(&a11, &u, 16);
}

// ================= k_prep: detect + cvt/norm + out-GEMM + zero state =========
__global__ __launch_bounds__(TPB) void k_prep(Ptrs P) {
  __shared__ union { float fred[TPB]; double dred[TPB]; } sm;
  __shared__ int flag;
  int bid = blockIdx.x, tid = threadIdx.x;
  // grid-stride zeroing of belowCnt + rowdone
  int ztot = P.B * NCLS + P.B;
  for (int i = bid * TPB + tid; i < ztot; i += P.gridPrep * TPB) {
    if (i < P.B * NCLS) P.belowCnt[i] = 0u; else P.rowdone[i - P.B * NCLS] = 0u;
  }
  if (bid < P.nCvt) {                       // ---- codes f32->f16 + per-block max norm
    float m = 0.0f;
    int n = bid * TPB + tid;
    if (n < P.N) {
      const float4* crow = (const float4*)(P.codes + (size_t)n * 64);
      uint4* orow = (uint4*)(P.codes16 + (size_t)n * 64);
      double c2 = 0.0;
#pragma unroll
      for (int i = 0; i < 8; ++i) {
        float4 qa = crow[2*i], qb = crow[2*i+1];
        c2 = fma((double)qa.x,(double)qa.x,c2); c2 = fma((double)qa.y,(double)qa.y,c2);
        c2 = fma((double)qa.z,(double)qa.z,c2); c2 = fma((double)qa.w,(double)qa.w,c2);
        c2 = fma((double)qb.x,(double)qb.x,c2); c2 = fma((double)qb.y,(double)qb.y,c2);
        c2 = fma((double)qb.z,(double)qb.z,c2); c2 = fma((double)qb.w,(double)qb.w,c2);
        uint4 o;
        o.x = packh2(qa.x, qa.y); o.y = packh2(qa.z, qa.w);
        o.z = packh2(qb.x, qb.y); o.w = packh2(qb.z, qb.w);
        orow[i] = o;
      }
      m = (float)(c2 * 1.000001);
    } else if (n < P.Npad) {
      uint4* orow = (uint4*)(P.codes16 + (size_t)n * 64);
      uint4 z = {0u,0u,0u,0u};
#pragma unroll
      for (int i = 0; i < 8; ++i) orow[i] = z;
    }
    sm.fred[tid] = m; __syncthreads();
    for (int off = 128; off > 0; off >>= 1) {
      if (tid < off) sm.fred[tid] = fmaxf(sm.fred[tid], sm.fred[tid + off]);
      __syncthreads();
    }
    if (tid == 0) P.pmax[bid] = sm.fred[0];
  } else if (bid < P.nCvt + P.B) {          // ---- out row b = x@W (f64 + f16)
    if (tid == 0) P.pmax[bid] = 0.0f;
    int b = bid - P.nCvt;
    int t = tid & 63, w = tid >> 6;        // 4 K-chunks x 8 accumulators
    int kc = P.D >> 2;
    const float* xr = P.x + (size_t)b * P.D;
    double a[8];
#pragma unroll
    for (int j = 0; j < 8; ++j) a[j] = 0.0;
    for (int k = w * kc; k < (w + 1) * kc; k += 8) {
      float4 xv0 = *(const float4*)(xr + k);
      float4 xv1 = *(const float4*)(xr + k + 4);
      float xs[8] = {xv0.x, xv0.y, xv0.z, xv0.w, xv1.x, xv1.y, xv1.z, xv1.w};
#pragma unroll
      for (int j = 0; j < 8; ++j)
        a[j] = fma((double)xs[j], (double)P.W[(size_t)(k + j) * 64 + t], a[j]);
    }
    sm.dred[tid] = ((a[0]+a[1])+(a[2]+a[3])) + ((a[4]+a[5])+(a[6]+a[7]));
    __syncthreads();
    double o = 0.0;
    if (w == 0) {
      o = sm.dred[t] + sm.dred[64+t] + sm.dred[128+t] + sm.dred[192+t];
      P.out64[(size_t)b * 64 + t] = o;
      P.out16[(size_t)b * 64 + t] = f2h((float)o);
    }
    __syncthreads();
    if (w == 0) sm.dred[t] = o * o;
    __syncthreads();
    if (tid == 0) {
      double s = 0.0;
      for (int i = 0; i < 64; ++i) s += sm.dred[i];
      P.B1sq[b] = s;
    }
  } else {                                  // ---- detect labels dtype
    if (tid == 0) { P.pmax[bid] = 0.0f; flag = 0; }
    __syncthreads();
    int mm = P.N < 256 ? P.N : 256;
    if (tid < mm && P.labels[2 * tid + 1] != 0) atomicOr(&flag, 1);
    __syncthreads();
    if (tid == 0) *P.shiftp = flag ? 0 : 1;  // label(n) = labels[n << shift]
  }
}

// ============ k_gemmhist: MFMA screen -> f16 scores + u16 hist slabs =========
__global__ __launch_bounds__(TPB) void k_gemmhist(Ptrs P) {
  __shared__ unsigned hist[MROWS * NBK];     // 32 KB
  __shared__ float sP[MROWS], sQ[MROWS], scr[TPB];
  int tid = threadIdx.x;
  int cx = blockIdx.x, m0 = blockIdx.y * MROWS;
  float cmax = reduce_cmax(P.pmax, P.gridPrep, scr);
  for (int i = tid; i < MROWS * NBK; i += TPB) hist[i] = 0u;
  if (tid < MROWS) {
    double lo, inv, bw;
    rowRange(P.B1sq[m0 + tid], (double)cmax, lo, inv, bw);
    sP[tid] = (float)(-0.5 * inv);           // bucket = trunc(d*P + Q), monotone
    sQ[tid] = (float)((50.0 - lo) * inv);
  }
  __syncthreads();
  int l = tid & 63, w = tid >> 6, quad = l >> 4, mr = l & 15;
  half8 a00, a01, a10, a11;
  loadA(P.out16, m0, mr, quad, a00, a01, a10, a11);
  float Pv0[4], Qv0[4], Pv1[4], Qv1[4];
#pragma unroll
  for (int r = 0; r < 4; ++r) {
    Pv0[r] = sP[quad*4 + r];      Qv0[r] = sQ[quad*4 + r];
    Pv1[r] = sP[16 + quad*4 + r]; Qv1[r] = sQ[16 + quad*4 + r];
  }
  int cstart = cx * P.cpb;
  int cend = cstart + P.cpb; if (cend > P.N) cend = P.N;
  const uint4* c4 = (const uint4*)P.codes16;
  floatx4 z = {0.f, 0.f, 0.f, 0.f};
  for (int base = cstart; base < cend; base += 64) {
    int nrow = base + w * 16 + mr;
    int nc = nrow < P.Npad ? nrow : P.Npad - 1;
    uint4 ub0 = c4[(size_t)nc * 8 + quad];
    uint4 ub1 = c4[(size_t)nc * 8 + 4 + quad];
    half8 b0, b1;
    __builtin_memcpy(&b0, &ub0, 16); __builtin_memcpy(&b1, &ub1, 16);
    floatx4 d0 = __builtin_amdgcn_mfma_f32_16x16x32_f16(a00, b0, z, 0, 0, 0);
    d0 = __builtin_amdgcn_mfma_f32_16x16x32_f16(a01, b1, d0, 0, 0, 0);
    floatx4 d1 = __builtin_amdgcn_mfma_f32_16x16x32_f16(a10, b0, z, 0, 0, 0);
    d1 = __builtin_amdgcn_mfma_f32_16x16x32_f16(a11, b1, d1, 0, 0, 0);
    if (nrow < P.N) {
#pragma unroll
      for (int r = 0; r < 4; ++r) {
        float v0 = fmaf(d0[r], -0.5f, 50.0f);
        P.simh[(size_t)(m0 + quad*4 + r) * P.N + nrow] = f2h(v0);
        int bk0 = (int)fmaf(d0[r], Pv0[r], Qv0[r]);
        bk0 = bk0 < 0 ? 0 : (bk0 > NBK-1 ? NBK-1 : bk0);
        atomicAdd(&hist[(quad*4 + r) * NBK + bk0], 1u);
        float v1 = fmaf(d1[r], -0.5f, 50.0f);
        P.simh[(size_t)(m0 + 16 + quad*4 + r) * P.N + nrow] = f2h(v1);
        int bk1 = (int)fmaf(d1[r], Pv1[r], Qv1[r]);
        bk1 = bk1 < 0 ? 0 : (bk1 > NBK-1 ? NBK-1 : bk1);
        atomicAdd(&hist[(16 + quad*4 + r) * NBK + bk1], 1u);
      }
    }
  }
  __syncthreads();
  for (int i = tid; i < MROWS * NBK; i += TPB)   // exclusive u16 slab, plain stores
    P.histg[((size_t)cx * P.B + (m0 + (i >> 8))) * NBK + (i & (NBK - 1))] =
        (unsigned short)hist[i];
}

// ============ k_scan: slab sum + prefix scan -> [TL,TH] per row ==============
__global__ __launch_bounds__(NBK) void k_scan(Ptrs P) {
  __shared__ unsigned s[NBK];
  __shared__ float scr[TPB];
  int b = blockIdx.x, tid = threadIdx.x;
  float cmax = reduce_cmax(P.pmax, P.gridPrep, scr);
  unsigned acc = 0;
  for (int cx = 0; cx < NCHX; ++cx)
    acc += P.histg[((size_t)cx * P.B + b) * NBK + tid];   // coalesced u16
  s[tid] = acc;
  __syncthreads();
  for (int off = 1; off < NBK; off <<= 1) {
    unsigned add = (tid >= off) ? s[tid - off] : 0u;
    __syncthreads();
    s[tid] += add;
    __syncthreads();
  }
  unsigned K = (unsigned)P.Kp[0];
  unsigned cum = s[tid], prev = tid ? s[tid - 1] : 0u;
  if (cum >= K && prev < K) {              // exactly one thread: tb = tid
    double lo, inv, bw;
    rowRange(P.B1sq[b], (double)cmax, lo, inv, bw);
    double S = sqrt(P.B1sq[b] * (double)cmax);
    // M: f16 input cvt + f32 accum + f16 STORE quantization (2x slack each)
    double M = 0.5 * S * 1.1e-3 + (50.0 + 0.55 * S) * 0x1p-10 + 0.05;
    double lot = lo + (double)tid * bw;
    P.rowTH[b] = make_float2((float)(lot - 2.0 * M - 1e-3),
                             (float)(lot + bw + 2.0 * M + 1e-3));
  }
}

// ====== k_classfinal: stream scores; last chunk-block per row resolves =======
__global__ __launch_bounds__(TPB) void k_classfinal(Ptrs P) {
  __shared__ union {
    struct { unsigned lab[NCLS]; unsigned cnt; } c;
    struct { double key[CAPC]; int kidx[CAPC]; unsigned lab[NCLS];
             int soff[NCCH + 1]; unsigned btot; } f;
  } sm;
  __shared__ int isLast;
  int b = blockIdx.y, ch = blockIdx.x, tid = threadIdx.x;
  // ---- classify my chunk of row b ----
  for (int i = tid; i < NCLS; i += TPB) sm.c.lab[i] = 0u;
  if (tid == 0) sm.c.cnt = 0u;
  __syncthreads();
  float2 th = P.rowTH[b];
  float TL = th.x, TH = th.y;
  int shift = *P.shiftp;
  const unsigned short* rp = P.simh + (size_t)b * P.N;
  const uint4* rp4 = (const uint4*)rp;
  int nu4 = P.N >> 3;
  int q = (nu4 + NCCH - 1) / NCCH;
  int i0 = ch * q, i1 = i0 + q; if (i1 > nu4) i1 = nu4;
  unsigned* seg = P.cand + ((size_t)ch * P.B + b) * CAPB;
  for (int i = i0 + tid; i < i1; i += TPB) {
    uint4 u = rp4[i];
    unsigned uu[4] = {u.x, u.y, u.z, u.w};
#pragma unroll
    for (int k = 0; k < 8; ++k) {
      unsigned short us = (unsigned short)((uu[k >> 1] >> ((k & 1) * 16)) & 0xFFFFu);
      float hv = h2f(us);
      if (hv < TL) {
        atomicAdd(&sm.c.lab[P.labels[(size_t)(i*8 + k) << shift]], 1u);
      } else if (hv <= TH) {
        unsigned pos = atomicAdd(&sm.c.cnt, 1u);
        if (pos < CAPB) seg[pos] = (unsigned)(i*8 + k);
      }
    }
  }
  if (ch == NCCH - 1) {                    // N%8 tail
    for (int n = (nu4 << 3) + tid; n < P.N; n += TPB) {
      float hv = h2f(rp[n]);
      if (hv < TL) {
        atomicAdd(&sm.c.lab[P.labels[(size_t)n << shift]], 1u);
      } else if (hv <= TH) {
        unsigned pos = atomicAdd(&sm.c.cnt, 1u);
        if (pos < CAPB) seg[pos] = (unsigned)n;
      }
    }
  }
  __syncthreads();
  if (tid == 0) {
    unsigned c = sm.c.cnt;
    P.ccnt[(size_t)ch * P.B + b] = c < CAPB ? c : CAPB;  // plain store
  }
  for (int i = tid; i < NCLS; i += TPB) {  // device-scope fire-and-forget merge
    unsigned c = sm.c.lab[i];
    if (c) atomicAdd(&P.belowCnt[b * NCLS + i], c);
  }
  __syncthreads();                          // drain all waves' stores to local L2
  if (tid == 0) {
    __threadfence();                        // agent release: L2 writeback
    unsigned prev = atomicAdd(&P.rowdone[b], 1u);
    isLast = (prev == NCCH - 1) ? 1 : 0;
    if (isLast) __threadfence();            // agent acquire: invalidate caches
  }
  __syncthreads();
  if (!isLast) return;
  // ---- final: gather segments, exact f64 resolve, emit probs ----
  if (tid == 0) {
    sm.f.btot = 0u;
    sm.f.soff[0] = 0;
    for (int s = 0; s < NCCH; ++s) {
      int nx = sm.f.soff[s] + (int)P.ccnt[(size_t)s * P.B + b];
      sm.f.soff[s + 1] = nx < CAPC ? nx : CAPC;
    }
  }
  __syncthreads();
  for (int c = tid; c < NCLS; c += TPB) {
    unsigned v = P.belowCnt[b * NCLS + c];
    if (v) atomicAdd(&sm.f.btot, v);
  }
  for (int s = 0; s < NCCH; ++s) {
    int c0 = sm.f.soff[s], len = sm.f.soff[s + 1] - c0;
    const unsigned* sg = P.cand + ((size_t)s * P.B + b) * CAPB;
    for (int j = tid; j < len; j += TPB) sm.f.kidx[c0 + j] = (int)sg[j];
  }
  __syncthreads();
  int cnt = sm.f.soff[NCCH];
  int K = P.Kp[0];
  int need = K - (int)sm.f.btot;
  int M = 1; while (M < cnt) M <<= 1;
  const double* od = P.out64 + (size_t)b * 64;
  for (int i = tid; i < M; i += TPB) {
    if (i < cnt) {
      sm.f.key[i] = fma(dot1(P.codes, sm.f.kidx[i], od), -0.5, 50.0);
    } else { sm.f.key[i] = __builtin_inf(); sm.f.kidx[i] = 0x7FFFFFFF; }
  }
  __syncthreads();
  for (int size = 2; size <= M; size <<= 1) {
    for (int stride = size >> 1; stride > 0; stride >>= 1) {
      for (int i = tid; i < M; i += TPB) {
        int j = i ^ stride;
        if (j > i) {
          double ki = sm.f.key[i], kj = sm.f.key[j];
          int ii = sm.f.kidx[i], ij = sm.f.kidx[j];
          bool up = ((i & size) == 0);
          bool sw = up ? (kj < ki || (kj == ki && ij < ii))
                       : (kj > ki || (kj == ki && ij > ii));
          if (sw) { sm.f.key[i] = kj; sm.f.key[j] = ki;
                    sm.f.kidx[i] = ij; sm.f.kidx[j] = ii; }
        }
      }
      __syncthreads();
    }
  }
  for (int i = tid; i < NCLS; i += TPB) sm.f.lab[i] = 0u;
  __syncthreads();
  int take = need < cnt ? need : cnt;
  if (take < 0) take = 0;
  for (int i = tid; i < take; i += TPB)
    atomicAdd(&sm.f.lab[P.labels[(size_t)sm.f.kidx[i] << shift]], 1u);
  __syncthreads();
  double Kd = (double)K;
  for (int c = tid; c < NCLS; c += TPB)
    P.outp[b * NCLS + c] = (float)((double)(P.belowCnt[b * NCLS + c] + sm.f.lab[c]) / Kd);
}

extern "C" void kernel_launch(void* const* d_in, const int* in_sizes, int n_in,
                              void* d_out, int out_size, void* d_ws, size_t ws_size,
                              hipStream_t stream) {
  Ptrs P;
  P.x      = (const float*)d_in[0];
  P.W      = (const float*)d_in[1];
  P.codes  = (const float*)d_in[2];
  P.labels = (const int*)d_in[3];
  P.Kp     = (const int*)d_in[4];
  P.B    = out_size / NCLS;                 // 256
  P.N    = in_sizes[3];                     // 100000
  P.D    = in_sizes[0] / P.B;               // 2048
  P.Npad = (P.N + 255) & ~255;              // 100096
  P.nCvt = P.Npad / 256;                    // 391
  P.gridPrep = P.nCvt + P.B + 1;            // cvt + out-rows + detect = 648
  P.cpb  = (((P.Npad + NCHX - 1) / NCHX) + 63) & ~63;  // 832
  P.outp = (float*)d_out;

  char* p = (char*)d_ws;
  P.out64    = (double*)p;         p += (size_t)P.B * 64 * sizeof(double);        // 128 KB
  P.out16    = (unsigned short*)p; p += (size_t)P.B * 64 * 2;                     // 32 KB
  P.B1sq     = (double*)p;         p += (size_t)P.B * sizeof(double);             // 2 KB
  P.rowTH    = (float2*)p;         p += (size_t)P.B * sizeof(float2);             // 2 KB
  P.shiftp   = (int*)p;            p += 64;
  P.pmax     = (float*)p;          p += 4096;                                     // 4 KB
  P.belowCnt = (unsigned*)p;       p += (size_t)P.B * NCLS * sizeof(unsigned);    // 100 KB
  P.ccnt     = (unsigned*)p;       p += (size_t)NCCH * P.B * sizeof(unsigned);    // 4 KB
  P.rowdone  = (unsigned*)p;       p += (size_t)P.B * sizeof(unsigned);           // 1 KB
  P.cand     = (unsigned*)p;       p += (size_t)NCCH * P.B * CAPB * sizeof(unsigned); // 2 MB
  P.histg    = (unsigned short*)p; p += (size_t)NCHX * P.B * NBK * 2;             // 16 MB
  P.codes16  = (unsigned short*)p; p += (size_t)P.Npad * 64 * 2;                  // 12.8 MB
  P.simh     = (unsigned short*)p;                                                // 51.2 MB

  k_prep<<<P.gridPrep, TPB, 0, stream>>>(P);
  k_gemmhist<<<dim3(NCHX, P.B / MROWS), TPB, 0, stream>>>(P);
  k_scan<<<P.B, NBK, 0, stream>>>(P);
  k_classfinal<<<dim3(NCCH, P.B), TPB, 0, stream>>>(P);
}

// Round 9
// 237.882 us; speedup vs baseline: 3.2718x; 1.2925x over previous
//
#include <hip/hip_runtime.h>

// B=256 queries, D=2048, d=64 hash dim, N=100000 database, C=100 classes,
// K=1000 SMALLEST-sim selection. Inputs f32, labels int, output f32.
//
// Exact-set algorithm (absmax 0 in R2..R8): MFMA f16 screening GEMM with
// rigorous error bound M vs f64 truth (|v64 - v_screen| <= M =
// 0.5*S*1.1e-3 + 0.05, S = ||out_b||*max||c||, Cauchy-Schwarz over f16-cvt +
// f32-accum errors; both screen passes recompute, each bounded by M):
//   v < TL = lo_tb - 2M  => certainly in f64 top-K  (label-counted)
//   v > TH = hi_tb + 2M  => certainly out
//   else                 => candidate (~370/row), exact f64 resolve.
//
// R9: R6's fence-free 4-phase split (every kernel <45us there) + R8's fused
// prep, 5 plain dispatches, no memsets, no device-scope fences (R8's fused
// classfinal spent ~160us in __threadfence L2 writebacks), no return-
// dependent global atomics (R5 lesson), no grid.sync (R7 lesson).

#define TPB 256
#define NBK 256          // buckets per row histogram
#define NCHX 128         // code-chunks (grid.x) for both MFMA passes
#define MROWS 32         // out-rows per MFMA block
#define CAPB 64          // per-(chunk,row) candidate capacity (expected ~3)
#define CAPC 1024        // per-row candidate capacity (expected ~370)
#define NCLS 100

typedef _Float16 half8 __attribute__((ext_vector_type(8)));
typedef float floatx4 __attribute__((ext_vector_type(4)));

struct Ptrs {
  const float* x; const float* W; const float* codes;
  const int* labels; const int* Kp;
  double* out64; double* B1sq; unsigned short* out16;
  float2* rowTH; int* shiftp; float* pmax;
  unsigned* belowCnt; unsigned* ccnt; unsigned* cand;
  unsigned short* histg; unsigned short* codes16;
  float* outp;
  int B, N, D, Npad, nCvt, gridPrep, cpb;
};

static __device__ __forceinline__ unsigned short f2h(float v) {
  _Float16 h = (_Float16)v; unsigned short u; __builtin_memcpy(&u, &h, 2); return u;
}
static __device__ __forceinline__ unsigned packh2(float a, float b) {
  return (unsigned)f2h(a) | ((unsigned)f2h(b) << 16);
}

static __device__ __forceinline__ void rowRange(double b1sq, double cmax,
                                                double& lo, double& inv, double& bw) {
  double hr = 0.5 * sqrt(b1sq * cmax) * 1.000001 + 9.0;  // +9 >> M
  lo = 50.0 - hr;
  bw = (2.0 * hr) / (double)NBK;
  inv = (double)NBK / (2.0 * hr);
}

static __device__ __forceinline__ double dot1(const float* __restrict__ codes, int n,
                                              const double* __restrict__ od) {
  const float4* crow = (const float4*)(codes + (size_t)n * 64);
  double a = 0.0;
#pragma unroll
  for (int i = 0; i < 16; ++i) {
    float4 q = crow[i];
    a = fma((double)q.x, od[i*4+0], a);
    a = fma((double)q.y, od[i*4+1], a);
    a = fma((double)q.z, od[i*4+2], a);
    a = fma((double)q.w, od[i*4+3], a);
  }
  return a;
}

static __device__ __forceinline__ float reduce_cmax(const float* __restrict__ pmax,
                                                    int n, float* scratch) {
  int tid = threadIdx.x;
  float m = 0.0f;
  for (int i = tid; i < n; i += TPB) m = fmaxf(m, pmax[i]);
  scratch[tid] = m; __syncthreads();
  for (int off = 128; off > 0; off >>= 1) {
    if (tid < off) scratch[tid] = fmaxf(scratch[tid], scratch[tid + off]);
    __syncthreads();
  }
  float r = scratch[0];
  __syncthreads();
  return r;
}

// MFMA A-fragment loader (mfma_f32_16x16x32_f16, m89-verified family):
//   A: lane holds A[m=lane&15][k=(lane>>4)*8+j]; D: reg r = D[(lane>>4)*4+r][lane&15]
static __device__ __forceinline__ void loadA(const unsigned short* __restrict__ out16,
                                             int m0, int mr, int quad,
                                             half8& a00, half8& a01, half8& a10, half8& a11) {
  const uint4* o4 = (const uint4*)out16;
  uint4 u;
  u = o4[(size_t)(m0 + mr) * 8 + quad];          __builtin_memcpy(&a00, &u, 16);
  u = o4[(size_t)(m0 + mr) * 8 + 4 + quad];      __builtin_memcpy(&a01, &u, 16);
  u = o4[(size_t)(m0 + 16 + mr) * 8 + quad];     __builtin_memcpy(&a10, &u, 16);
  u = o4[(size_t)(m0 + 16 + mr) * 8 + 4 + quad]; __builtin_memcpy(&a11, &u, 16);
}

// ================= k_prep: detect + cvt/norm + out-GEMM + zero state =========
__global__ __launch_bounds__(TPB) void k_prep(Ptrs P) {
  __shared__ union { float fred[TPB]; double dred[TPB]; } sm;
  __shared__ int flag;
  int bid = blockIdx.x, tid = threadIdx.x;
  for (int i = bid * TPB + tid; i < P.B * NCLS; i += P.gridPrep * TPB)
    P.belowCnt[i] = 0u;
  if (bid < P.nCvt) {                       // ---- codes f32->f16 + per-block max norm
    float m = 0.0f;
    int n = bid * TPB + tid;
    if (n < P.N) {
      const float4* crow = (const float4*)(P.codes + (size_t)n * 64);
      uint4* orow = (uint4*)(P.codes16 + (size_t)n * 64);
      double c2 = 0.0;
#pragma unroll
      for (int i = 0; i < 8; ++i) {
        float4 qa = crow[2*i], qb = crow[2*i+1];
        c2 = fma((double)qa.x,(double)qa.x,c2); c2 = fma((double)qa.y,(double)qa.y,c2);
        c2 = fma((double)qa.z,(double)qa.z,c2); c2 = fma((double)qa.w,(double)qa.w,c2);
        c2 = fma((double)qb.x,(double)qb.x,c2); c2 = fma((double)qb.y,(double)qb.y,c2);
        c2 = fma((double)qb.z,(double)qb.z,c2); c2 = fma((double)qb.w,(double)qb.w,c2);
        uint4 o;
        o.x = packh2(qa.x, qa.y); o.y = packh2(qa.z, qa.w);
        o.z = packh2(qb.x, qb.y); o.w = packh2(qb.z, qb.w);
        orow[i] = o;
      }
      m = (float)(c2 * 1.000001);
    } else if (n < P.Npad) {
      uint4* orow = (uint4*)(P.codes16 + (size_t)n * 64);
      uint4 z = {0u,0u,0u,0u};
#pragma unroll
      for (int i = 0; i < 8; ++i) orow[i] = z;
    }
    sm.fred[tid] = m; __syncthreads();
    for (int off = 128; off > 0; off >>= 1) {
      if (tid < off) sm.fred[tid] = fmaxf(sm.fred[tid], sm.fred[tid + off]);
      __syncthreads();
    }
    if (tid == 0) P.pmax[bid] = sm.fred[0];
  } else if (bid < P.nCvt + P.B) {          // ---- out row b = x@W (f64 + f16)
    if (tid == 0) P.pmax[bid] = 0.0f;
    int b = bid - P.nCvt;
    int t = tid & 63, w = tid >> 6;        // 4 K-chunks x 8 accumulators
    int kc = P.D >> 2;
    const float* xr = P.x + (size_t)b * P.D;
    double a[8];
#pragma unroll
    for (int j = 0; j < 8; ++j) a[j] = 0.0;
    for (int k = w * kc; k < (w + 1) * kc; k += 8) {
      float4 xv0 = *(const float4*)(xr + k);
      float4 xv1 = *(const float4*)(xr + k + 4);
      float xs[8] = {xv0.x, xv0.y, xv0.z, xv0.w, xv1.x, xv1.y, xv1.z, xv1.w};
#pragma unroll
      for (int j = 0; j < 8; ++j)
        a[j] = fma((double)xs[j], (double)P.W[(size_t)(k + j) * 64 + t], a[j]);
    }
    sm.dred[tid] = ((a[0]+a[1])+(a[2]+a[3])) + ((a[4]+a[5])+(a[6]+a[7]));
    __syncthreads();
    double o = 0.0;
    if (w == 0) {
      o = sm.dred[t] + sm.dred[64+t] + sm.dred[128+t] + sm.dred[192+t];
      P.out64[(size_t)b * 64 + t] = o;
      P.out16[(size_t)b * 64 + t] = f2h((float)o);
    }
    __syncthreads();
    if (w == 0) sm.dred[t] = o * o;
    __syncthreads();
    if (tid == 0) {
      double s = 0.0;
      for (int i = 0; i < 64; ++i) s += sm.dred[i];
      P.B1sq[b] = s;
    }
  } else {                                  // ---- detect labels dtype
    if (tid == 0) { P.pmax[bid] = 0.0f; flag = 0; }
    __syncthreads();
    int mm = P.N < 256 ? P.N : 256;
    if (tid < mm && P.labels[2 * tid + 1] != 0) atomicOr(&flag, 1);
    __syncthreads();
    if (tid == 0) *P.shiftp = flag ? 0 : 1;  // label(n) = labels[n << shift]
  }
}

// ============ k_gemmhist: MFMA screen -> per-(chunk,row) u16 hist slabs ======
__global__ __launch_bounds__(TPB) void k_gemmhist(Ptrs P) {
  __shared__ unsigned hist[MROWS * NBK];     // 32 KB
  __shared__ float sP[MROWS], sQ[MROWS], scr[TPB];
  int tid = threadIdx.x;
  int cx = blockIdx.x, m0 = blockIdx.y * MROWS;
  float cmax = reduce_cmax(P.pmax, P.gridPrep, scr);
  for (int i = tid; i < MROWS * NBK; i += TPB) hist[i] = 0u;
  if (tid < MROWS) {
    double lo, inv, bw;
    rowRange(P.B1sq[m0 + tid], (double)cmax, lo, inv, bw);
    sP[tid] = (float)(-0.5 * inv);           // bucket = trunc(d*P + Q), monotone
    sQ[tid] = (float)((50.0 - lo) * inv);
  }
  __syncthreads();
  int l = tid & 63, w = tid >> 6, quad = l >> 4, mr = l & 15;
  half8 a00, a01, a10, a11;
  loadA(P.out16, m0, mr, quad, a00, a01, a10, a11);
  float Pv0[4], Qv0[4], Pv1[4], Qv1[4];
#pragma unroll
  for (int r = 0; r < 4; ++r) {
    Pv0[r] = sP[quad*4 + r];      Qv0[r] = sQ[quad*4 + r];
    Pv1[r] = sP[16 + quad*4 + r]; Qv1[r] = sQ[16 + quad*4 + r];
  }
  int cstart = cx * P.cpb;
  int cend = cstart + P.cpb; if (cend > P.N) cend = P.N;
  const uint4* c4 = (const uint4*)P.codes16;
  floatx4 z = {0.f, 0.f, 0.f, 0.f};
  for (int base = cstart; base < cend; base += 64) {
    int nrow = base + w * 16 + mr;
    int nc = nrow < P.Npad ? nrow : P.Npad - 1;
    uint4 ub0 = c4[(size_t)nc * 8 + quad];
    uint4 ub1 = c4[(size_t)nc * 8 + 4 + quad];
    half8 b0, b1;
    __builtin_memcpy(&b0, &ub0, 16); __builtin_memcpy(&b1, &ub1, 16);
    floatx4 d0 = __builtin_amdgcn_mfma_f32_16x16x32_f16(a00, b0, z, 0, 0, 0);
    d0 = __builtin_amdgcn_mfma_f32_16x16x32_f16(a01, b1, d0, 0, 0, 0);
    floatx4 d1 = __builtin_amdgcn_mfma_f32_16x16x32_f16(a10, b0, z, 0, 0, 0);
    d1 = __builtin_amdgcn_mfma_f32_16x16x32_f16(a11, b1, d1, 0, 0, 0);
    if (nrow < P.N) {
#pragma unroll
      for (int r = 0; r < 4; ++r) {
        int bk0 = (int)fmaf(d0[r], Pv0[r], Qv0[r]);
        bk0 = bk0 < 0 ? 0 : (bk0 > NBK-1 ? NBK-1 : bk0);
        atomicAdd(&hist[(quad*4 + r) * NBK + bk0], 1u);     // LDS
        int bk1 = (int)fmaf(d1[r], Pv1[r], Qv1[r]);
        bk1 = bk1 < 0 ? 0 : (bk1 > NBK-1 ? NBK-1 : bk1);
        atomicAdd(&hist[(16 + quad*4 + r) * NBK + bk1], 1u);
      }
    }
  }
  __syncthreads();
  for (int i = tid; i < MROWS * NBK; i += TPB)   // exclusive u16 slab, plain stores
    P.histg[((size_t)cx * P.B + (m0 + (i >> 8))) * NBK + (i & (NBK - 1))] =
        (unsigned short)hist[i];
}

// ============ k_scan: slab sum + prefix scan -> [TL,TH] per row ==============
__global__ __launch_bounds__(NBK) void k_scan(Ptrs P) {
  __shared__ unsigned s[NBK];
  __shared__ float scr[TPB];
  int b = blockIdx.x, tid = threadIdx.x;
  float cmax = reduce_cmax(P.pmax, P.gridPrep, scr);
  unsigned acc = 0;
  for (int cx = 0; cx < NCHX; ++cx)
    acc += P.histg[((size_t)cx * P.B + b) * NBK + tid];   // coalesced u16
  s[tid] = acc;
  __syncthreads();
  for (int off = 1; off < NBK; off <<= 1) {
    unsigned add = (tid >= off) ? s[tid - off] : 0u;
    __syncthreads();
    s[tid] += add;
    __syncthreads();
  }
  unsigned K = (unsigned)P.Kp[0];
  unsigned cum = s[tid], prev = tid ? s[tid - 1] : 0u;
  if (cum >= K && prev < K) {              // exactly one thread: tb = tid
    double lo, inv, bw;
    rowRange(P.B1sq[b], (double)cmax, lo, inv, bw);
    double S = sqrt(P.B1sq[b] * (double)cmax);
    double M = 0.5 * S * 1.1e-3 + 0.05;    // f16 cvt + f32 accum bound
    double lot = lo + (double)tid * bw;
    P.rowTH[b] = make_float2((float)(lot - 2.0 * M - 1e-3),
                             (float)(lot + bw + 2.0 * M + 1e-3));
  }
}

// ====== k_mclass: MFMA recompute -> below label-hist / candidate segments ====
__global__ __launch_bounds__(TPB) void k_mclass(Ptrs P) {
  __shared__ unsigned lab[MROWS * NCLS];   // 12.8 KB
  __shared__ unsigned lcnt[MROWS];
  __shared__ float sTL[MROWS], sTH[MROWS];
  int tid = threadIdx.x;
  int cx = blockIdx.x, m0 = blockIdx.y * MROWS;
  for (int i = tid; i < MROWS * NCLS; i += TPB) lab[i] = 0u;
  if (tid < MROWS) {
    lcnt[tid] = 0u;
    float2 th = P.rowTH[m0 + tid];
    sTL[tid] = th.x; sTH[tid] = th.y;
  }
  __syncthreads();
  int l = tid & 63, w = tid >> 6, quad = l >> 4, mr = l & 15;
  half8 a00, a01, a10, a11;
  loadA(P.out16, m0, mr, quad, a00, a01, a10, a11);
  float TL0[4], TH0[4], TL1[4], TH1[4];
#pragma unroll
  for (int r = 0; r < 4; ++r) {
    TL0[r] = sTL[quad*4 + r];      TH0[r] = sTH[quad*4 + r];
    TL1[r] = sTL[16 + quad*4 + r]; TH1[r] = sTH[16 + quad*4 + r];
  }
  int shift = *P.shiftp;
  int cstart = cx * P.cpb;
  int cend = cstart + P.cpb; if (cend > P.N) cend = P.N;
  const uint4* c4 = (const uint4*)P.codes16;
  floatx4 z = {0.f, 0.f, 0.f, 0.f};
  for (int base = cstart; base < cend; base += 64) {
    int nrow = base + w * 16 + mr;
    int nc = nrow < P.Npad ? nrow : P.Npad - 1;
    uint4 ub0 = c4[(size_t)nc * 8 + quad];
    uint4 ub1 = c4[(size_t)nc * 8 + 4 + quad];
    half8 b0, b1;
    __builtin_memcpy(&b0, &ub0, 16); __builtin_memcpy(&b1, &ub1, 16);
    int nl = nrow < P.N ? nrow : P.N - 1;
    int lv = P.labels[(size_t)nl << shift];
    floatx4 d0 = __builtin_amdgcn_mfma_f32_16x16x32_f16(a00, b0, z, 0, 0, 0);
    d0 = __builtin_amdgcn_mfma_f32_16x16x32_f16(a01, b1, d0, 0, 0, 0);
    floatx4 d1 = __builtin_amdgcn_mfma_f32_16x16x32_f16(a10, b0, z, 0, 0, 0);
    d1 = __builtin_amdgcn_mfma_f32_16x16x32_f16(a11, b1, d1, 0, 0, 0);
    if (nrow < P.N) {
#pragma unroll
      for (int r = 0; r < 4; ++r) {
        int rl0 = quad*4 + r, rl1 = 16 + quad*4 + r;
        float v0 = fmaf(d0[r], -0.5f, 50.0f);
        if (v0 < TL0[r]) {
          atomicAdd(&lab[rl0 * NCLS + lv], 1u);                  // LDS
        } else if (v0 <= TH0[r]) {
          unsigned pos = atomicAdd(&lcnt[rl0], 1u);              // LDS, local
          if (pos < CAPB)
            P.cand[((size_t)cx * P.B + (m0 + rl0)) * CAPB + pos] = (unsigned)nrow;
        }
        float v1 = fmaf(d1[r], -0.5f, 50.0f);
        if (v1 < TL1[r]) {
          atomicAdd(&lab[rl1 * NCLS + lv], 1u);
        } else if (v1 <= TH1[r]) {
          unsigned pos = atomicAdd(&lcnt[rl1], 1u);
          if (pos < CAPB)
            P.cand[((size_t)cx * P.B + (m0 + rl1)) * CAPB + pos] = (unsigned)nrow;
        }
      }
    }
  }
  __syncthreads();
  if (tid < MROWS) {
    unsigned c = lcnt[tid];
    P.ccnt[(size_t)cx * P.B + (m0 + tid)] = c < CAPB ? c : CAPB;  // plain store
  }
  for (int i = tid; i < MROWS * NCLS; i += TPB) {  // fire-and-forget merge
    unsigned c = lab[i];
    if (c) atomicAdd(&P.belowCnt[(m0 + i / NCLS) * NCLS + i % NCLS], c);
  }
}

// ============ k_final: gather segments, exact f64 resolve, emit ==============
__global__ __launch_bounds__(TPB) void k_final(Ptrs P) {
  __shared__ double key[CAPC];
  __shared__ int kidx[CAPC];
  __shared__ unsigned lab[NCLS];
  __shared__ int soff[NCHX + 1];
  __shared__ unsigned btot;
  int b = blockIdx.x, tid = threadIdx.x;
  if (tid == 0) {
    btot = 0u;
    soff[0] = 0;
    for (int s = 0; s < NCHX; ++s) {
      int nx = soff[s] + (int)P.ccnt[(size_t)s * P.B + b];
      soff[s + 1] = nx < CAPC ? nx : CAPC;
    }
  }
  __syncthreads();
  for (int c = tid; c < NCLS; c += TPB) {
    unsigned v = P.belowCnt[b * NCLS + c];
    if (v) atomicAdd(&btot, v);
  }
  for (int s = tid; s < NCHX; s += TPB) {  // one thread per segment (~3 each)
    int c0 = soff[s], len = soff[s + 1] - c0;
    const unsigned* sg = P.cand + ((size_t)s * P.B + b) * CAPB;
    for (int j = 0; j < len; ++j) kidx[c0 + j] = (int)sg[j];
  }
  __syncthreads();
  int cnt = soff[NCHX];
  int K = P.Kp[0];
  int need = K - (int)btot;
  int M = 1; while (M < cnt) M <<= 1;
  const double* od = P.out64 + (size_t)b * 64;
  for (int i = tid; i < M; i += TPB) {
    if (i < cnt) {
      key[i] = fma(dot1(P.codes, kidx[i], od), -0.5, 50.0);
    } else { key[i] = __builtin_inf(); kidx[i] = 0x7FFFFFFF; }
  }
  __syncthreads();
  for (int size = 2; size <= M; size <<= 1) {
    for (int stride = size >> 1; stride > 0; stride >>= 1) {
      for (int i = tid; i < M; i += TPB) {
        int j = i ^ stride;
        if (j > i) {
          double ki = key[i], kj = key[j];
          int ii = kidx[i], ij = kidx[j];
          bool up = ((i & size) == 0);
          bool sw = up ? (kj < ki || (kj == ki && ij < ii))
                       : (kj > ki || (kj == ki && ij > ii));
          if (sw) { key[i] = kj; key[j] = ki; kidx[i] = ij; kidx[j] = ii; }
        }
      }
      __syncthreads();
    }
  }
  for (int i = tid; i < NCLS; i += TPB) lab[i] = 0u;
  __syncthreads();
  int shift = *P.shiftp;
  int take = need < cnt ? need : cnt;
  if (take < 0) take = 0;
  for (int i = tid; i < take; i += TPB)
    atomicAdd(&lab[P.labels[(size_t)kidx[i] << shift]], 1u);
  __syncthreads();
  double Kd = (double)K;
  for (int c = tid; c < NCLS; c += TPB)
    P.outp[b * NCLS + c] = (float)((double)(P.belowCnt[b * NCLS + c] + lab[c]) / Kd);
}

extern "C" void kernel_launch(void* const* d_in, const int* in_sizes, int n_in,
                              void* d_out, int out_size, void* d_ws, size_t ws_size,
                              hipStream_t stream) {
  Ptrs P;
  P.x      = (const float*)d_in[0];
  P.W      = (const float*)d_in[1];
  P.codes  = (const float*)d_in[2];
  P.labels = (const int*)d_in[3];
  P.Kp     = (const int*)d_in[4];
  P.B    = out_size / NCLS;                 // 256
  P.N    = in_sizes[3];                     // 100000
  P.D    = in_sizes[0] / P.B;               // 2048
  P.Npad = (P.N + 255) & ~255;              // 100096
  P.nCvt = P.Npad / 256;                    // 391
  P.gridPrep = P.nCvt + P.B + 1;            // cvt + out-rows + detect = 648
  P.cpb  = (((P.Npad + NCHX - 1) / NCHX) + 63) & ~63;  // 832
  P.outp = (float*)d_out;

  char* p = (char*)d_ws;
  P.out64    = (double*)p;         p += (size_t)P.B * 64 * sizeof(double);        // 128 KB
  P.out16    = (unsigned short*)p; p += (size_t)P.B * 64 * 2;                     // 32 KB
  P.B1sq     = (double*)p;         p += (size_t)P.B * sizeof(double);             // 2 KB
  P.rowTH    = (float2*)p;         p += (size_t)P.B * sizeof(float2);             // 2 KB
  P.shiftp   = (int*)p;            p += 64;
  P.pmax     = (float*)p;          p += 4096;                                     // 4 KB
  P.belowCnt = (unsigned*)p;       p += (size_t)P.B * NCLS * sizeof(unsigned);    // 100 KB
  P.ccnt     = (unsigned*)p;       p += (size_t)NCHX * P.B * sizeof(unsigned);    // 128 KB
  P.cand     = (unsigned*)p;       p += (size_t)NCHX * P.B * CAPB * sizeof(unsigned); // 8 MB
  P.histg    = (unsigned short*)p; p += (size_t)NCHX * P.B * NBK * 2;             // 16 MB
  P.codes16  = (unsigned short*)p;                                                // 12.8 MB

  k_prep<<<P.gridPrep, TPB, 0, stream>>>(P);
  k_gemmhist<<<dim3(NCHX, P.B / MROWS), TPB, 0, stream>>>(P);
  k_scan<<<P.B, NBK, 0, stream>>>(P);
  k_mclass<<<dim3(NCHX, P.B / MROWS), TPB, 0, stream>>>(P);
  k_final<<<P.B, TPB, 0, stream>>>(P);
}

// Round 10
// 208.619 us; speedup vs baseline: 3.7308x; 1.1403x over previous
//
#include <hip/hip_runtime.h>

// B=256 queries, D=2048, d=64 hash dim, N=100000 database, C=100 classes,
// K=1000 SMALLEST-sim selection. Inputs f32, labels int, output f32.
//
// Exact-set algorithm (absmax 0 in R2..R9): MFMA f16 screening GEMM, scores
// stored as f16; rigorous bound |v64 - stored_score| <= M =
// 0.5*S*1.1e-3 + (50+0.55S)*2^-10 + 0.05  (S = ||out_b||*max||c||;
// f16-cvt of inputs + f32 MFMA accum + f16 store, each with 2x slack):
//   score < TL = lo_tb - 2M  => certainly in f64 top-K  (label-counted)
//   score > TH = hi_tb + 2M  => certainly out
//   else                     => candidate (~400/row), exact f64 resolve.
//
// R10: THREE dispatches. Everything after the screen GEMM is per-row local,
// so one block owns one row end-to-end (no cross-block state, no fences
// [R8 lesson], no grid.sync [R7], no return-dependent global atomics [R5],
// no histg slab round-trip, no serial ccnt scan [R9's k_final sink]):
//   k_prep  : detect labels dtype + codes f32->f16 + pmax + out=x@W (f64+f16)
//   k_sim   : MFMA screen -> f16 score matrix simh (store only, no hist)
//   k_rowall: per row: stream scores -> LDS hist -> scan -> [TL,TH] ->
//             re-stream -> classify -> exact f64 resolve -> emit probs.

#define TPB 256
#define TPF 1024         // threads for k_rowall
#define NBK 256          // buckets per row histogram
#define NCHX 128         // code-chunks (grid.x) for k_sim
#define MROWS 32         // out-rows per k_sim block
#define CAPC 2048        // per-row candidate capacity (expected ~400)
#define NCLS 100

typedef _Float16 half8 __attribute__((ext_vector_type(8)));
typedef float floatx4 __attribute__((ext_vector_type(4)));

struct Ptrs {
  const float* x; const float* W; const float* codes;
  const int* labels; const int* Kp;
  double* out64; double* B1sq; unsigned short* out16;
  int* shiftp; float* pmax;
  unsigned short* codes16; unsigned short* simh;
  float* outp;
  int B, N, D, Npad, nCvt, gridPrep, cpb;
};

static __device__ __forceinline__ unsigned short f2h(float v) {
  _Float16 h = (_Float16)v; unsigned short u; __builtin_memcpy(&u, &h, 2); return u;
}
static __device__ __forceinline__ float h2f(unsigned short u) {
  _Float16 h; __builtin_memcpy(&h, &u, 2); return (float)h;
}
static __device__ __forceinline__ unsigned packh2(float a, float b) {
  return (unsigned)f2h(a) | ((unsigned)f2h(b) << 16);
}

static __device__ __forceinline__ void rowRange(double b1sq, double cmax,
                                                double& lo, double& inv, double& bw) {
  double hr = 0.5 * sqrt(b1sq * cmax) * 1.000001 + 9.0;  // +9 > M: scores stay in range
  lo = 50.0 - hr;
  bw = (2.0 * hr) / (double)NBK;
  inv = (double)NBK / (2.0 * hr);
}

static __device__ __forceinline__ double dot1(const float* __restrict__ codes, int n,
                                              const double* __restrict__ od) {
  const float4* crow = (const float4*)(codes + (size_t)n * 64);
  double a = 0.0;
#pragma unroll
  for (int i = 0; i < 16; ++i) {
    float4 q = crow[i];
    a = fma((double)q.x, od[i*4+0], a);
    a = fma((double)q.y, od[i*4+1], a);
    a = fma((double)q.z, od[i*4+2], a);
    a = fma((double)q.w, od[i*4+3], a);
  }
  return a;
}

// MFMA A-fragment loader (mfma_f32_16x16x32_f16, m89-verified family):
//   A: lane holds A[m=lane&15][k=(lane>>4)*8+j]; D: reg r = D[(lane>>4)*4+r][lane&15]
static __device__ __forceinline__ void loadA(const unsigned short* __restrict__ out16,
                                             int m0, int mr, int quad,
                                             half8& a00, half8& a01, half8& a10, half8& a11) {
  const uint4* o4 = (const uint4*)out16;
  uint4 u;
  u = o4[(size_t)(m0 + mr) * 8 + quad];          __builtin_memcpy(&a00, &u, 16);
  u = o4[(size_t)(m0 + mr) * 8 + 4 + quad];      __builtin_memcpy(&a01, &u, 16);
  u = o4[(size_t)(m0 + 16 + mr) * 8 + quad];     __builtin_memcpy(&a10, &u, 16);
  u = o4[(size_t)(m0 + 16 + mr) * 8 + 4 + quad]; __builtin_memcpy(&a11, &u, 16);
}

// ================= k_prep: detect + cvt/norm + out-GEMM =================
__global__ __launch_bounds__(TPB) void k_prep(Ptrs P) {
  __shared__ union { float fred[TPB]; double dred[TPB]; } sm;
  __shared__ int flag;
  int bid = blockIdx.x, tid = threadIdx.x;
  if (bid < P.nCvt) {                       // ---- codes f32->f16 + per-block max norm
    float m = 0.0f;
    int n = bid * TPB + tid;
    if (n < P.N) {
      const float4* crow = (const float4*)(P.codes + (size_t)n * 64);
      uint4* orow = (uint4*)(P.codes16 + (size_t)n * 64);
      double c2 = 0.0;
#pragma unroll
      for (int i = 0; i < 8; ++i) {
        float4 qa = crow[2*i], qb = crow[2*i+1];
        c2 = fma((double)qa.x,(double)qa.x,c2); c2 = fma((double)qa.y,(double)qa.y,c2);
        c2 = fma((double)qa.z,(double)qa.z,c2); c2 = fma((double)qa.w,(double)qa.w,c2);
        c2 = fma((double)qb.x,(double)qb.x,c2); c2 = fma((double)qb.y,(double)qb.y,c2);
        c2 = fma((double)qb.z,(double)qb.z,c2); c2 = fma((double)qb.w,(double)qb.w,c2);
        uint4 o;
        o.x = packh2(qa.x, qa.y); o.y = packh2(qa.z, qa.w);
        o.z = packh2(qb.x, qb.y); o.w = packh2(qb.z, qb.w);
        orow[i] = o;
      }
      m = (float)(c2 * 1.000001);
    } else if (n < P.Npad) {
      uint4* orow = (uint4*)(P.codes16 + (size_t)n * 64);
      uint4 z = {0u,0u,0u,0u};
#pragma unroll
      for (int i = 0; i < 8; ++i) orow[i] = z;
    }
    sm.fred[tid] = m; __syncthreads();
    for (int off = 128; off > 0; off >>= 1) {
      if (tid < off) sm.fred[tid] = fmaxf(sm.fred[tid], sm.fred[tid + off]);
      __syncthreads();
    }
    if (tid == 0) P.pmax[bid] = sm.fred[0];
  } else if (bid < P.nCvt + P.B) {          // ---- out row b = x@W (f64 + f16)
    if (tid == 0) P.pmax[bid] = 0.0f;
    int b = bid - P.nCvt;
    int t = tid & 63, w = tid >> 6;        // 4 K-chunks x 8 accumulators
    int kc = P.D >> 2;
    const float* xr = P.x + (size_t)b * P.D;
    double a[8];
#pragma unroll
    for (int j = 0; j < 8; ++j) a[j] = 0.0;
    for (int k = w * kc; k < (w + 1) * kc; k += 8) {
      float4 xv0 = *(const float4*)(xr + k);
      float4 xv1 = *(const float4*)(xr + k + 4);
      float xs[8] = {xv0.x, xv0.y, xv0.z, xv0.w, xv1.x, xv1.y, xv1.z, xv1.w};
#pragma unroll
      for (int j = 0; j < 8; ++j)
        a[j] = fma((double)xs[j], (double)P.W[(size_t)(k + j) * 64 + t], a[j]);
    }
    sm.dred[tid] = ((a[0]+a[1])+(a[2]+a[3])) + ((a[4]+a[5])+(a[6]+a[7]));
    __syncthreads();
    double o = 0.0;
    if (w == 0) {
      o = sm.dred[t] + sm.dred[64+t] + sm.dred[128+t] + sm.dred[192+t];
      P.out64[(size_t)b * 64 + t] = o;
      P.out16[(size_t)b * 64 + t] = f2h((float)o);
    }
    __syncthreads();
    if (w == 0) sm.dred[t] = o * o;
    __syncthreads();
    if (tid == 0) {
      double s = 0.0;
      for (int i = 0; i < 64; ++i) s += sm.dred[i];
      P.B1sq[b] = s;
    }
  } else {                                  // ---- detect labels dtype
    if (tid == 0) { P.pmax[bid] = 0.0f; flag = 0; }
    __syncthreads();
    int mm = P.N < 256 ? P.N : 256;
    if (tid < mm && P.labels[2 * tid + 1] != 0) atomicOr(&flag, 1);
    __syncthreads();
    if (tid == 0) *P.shiftp = flag ? 0 : 1;  // label(n) = labels[n << shift]
  }
}

// ============ k_sim: MFMA screen -> f16 score matrix (store only) ============
__global__ __launch_bounds__(TPB) void k_sim(Ptrs P) {
  int tid = threadIdx.x;
  int cx = blockIdx.x, m0 = blockIdx.y * MROWS;
  int l = tid & 63, w = tid >> 6, quad = l >> 4, mr = l & 15;
  half8 a00, a01, a10, a11;
  loadA(P.out16, m0, mr, quad, a00, a01, a10, a11);
  int cstart = cx * P.cpb;
  int cend = cstart + P.cpb; if (cend > P.N) cend = P.N;
  const uint4* c4 = (const uint4*)P.codes16;
  floatx4 z = {0.f, 0.f, 0.f, 0.f};
  for (int base = cstart; base < cend; base += 64) {
    int nrow = base + w * 16 + mr;
    int nc = nrow < P.Npad ? nrow : P.Npad - 1;
    uint4 ub0 = c4[(size_t)nc * 8 + quad];
    uint4 ub1 = c4[(size_t)nc * 8 + 4 + quad];
    half8 b0, b1;
    __builtin_memcpy(&b0, &ub0, 16); __builtin_memcpy(&b1, &ub1, 16);
    floatx4 d0 = __builtin_amdgcn_mfma_f32_16x16x32_f16(a00, b0, z, 0, 0, 0);
    d0 = __builtin_amdgcn_mfma_f32_16x16x32_f16(a01, b1, d0, 0, 0, 0);
    floatx4 d1 = __builtin_amdgcn_mfma_f32_16x16x32_f16(a10, b0, z, 0, 0, 0);
    d1 = __builtin_amdgcn_mfma_f32_16x16x32_f16(a11, b1, d1, 0, 0, 0);
    if (nrow < P.N) {
#pragma unroll
      for (int r = 0; r < 4; ++r) {
        P.simh[(size_t)(m0 + quad*4 + r) * P.N + nrow] = f2h(fmaf(d0[r], -0.5f, 50.0f));
        P.simh[(size_t)(m0 + 16 + quad*4 + r) * P.N + nrow] = f2h(fmaf(d1[r], -0.5f, 50.0f));
      }
    }
  }
}

// ==== k_rowall: per row: hist -> scan -> classify -> exact resolve -> emit ===
__global__ __launch_bounds__(TPF) void k_rowall(Ptrs P) {
  __shared__ double key[CAPC];              // 16 KB
  __shared__ int kidx[CAPC];                // 8 KB
  __shared__ unsigned hist[NBK];
  __shared__ unsigned lab[NCLS];
  __shared__ float scr[TPF];
  __shared__ float sTL, sTH;
  __shared__ unsigned cnt_s;
  int b = blockIdx.x, tid = threadIdx.x;
  // ---- cmax from pmax slots ----
  float m = 0.0f;
  for (int i = tid; i < P.gridPrep; i += TPF) m = fmaxf(m, P.pmax[i]);
  scr[tid] = m; __syncthreads();
  for (int off = TPF / 2; off > 0; off >>= 1) {
    if (tid < off) scr[tid] = fmaxf(scr[tid], scr[tid + off]);
    __syncthreads();
  }
  float cmax = scr[0];
  // ---- row range / bucket transform ----
  double lo, inv, bw;
  rowRange(P.B1sq[b], (double)cmax, lo, inv, bw);
  float fP = (float)inv, fQ = (float)(-lo * inv);   // bucket = trunc(v*fP + fQ)
  for (int i = tid; i < NBK; i += TPF) hist[i] = 0u;
  for (int i = tid; i < NCLS; i += TPF) lab[i] = 0u;
  if (tid == 0) cnt_s = 0u;
  __syncthreads();
  // ---- pass 1: histogram stored scores ----
  const unsigned short* rp = P.simh + (size_t)b * P.N;
  const uint4* rp4 = (const uint4*)rp;
  int nu4 = P.N >> 3;
  for (int i = tid; i < nu4; i += TPF) {
    uint4 u = rp4[i];
    unsigned uu[4] = {u.x, u.y, u.z, u.w};
#pragma unroll
    for (int k = 0; k < 8; ++k) {
      float v = h2f((unsigned short)((uu[k >> 1] >> ((k & 1) * 16)) & 0xFFFFu));
      int bk = (int)fmaf(v, fP, fQ);
      bk = bk < 0 ? 0 : (bk > NBK - 1 ? NBK - 1 : bk);
      atomicAdd(&hist[bk], 1u);
    }
  }
  for (int n = (nu4 << 3) + tid; n < P.N; n += TPF) {
    float v = h2f(rp[n]);
    int bk = (int)fmaf(v, fP, fQ);
    bk = bk < 0 ? 0 : (bk > NBK - 1 ? NBK - 1 : bk);
    atomicAdd(&hist[bk], 1u);
  }
  __syncthreads();
  // ---- inclusive scan of hist (first 256 threads) -> threshold bucket ----
  for (int off = 1; off < NBK; off <<= 1) {
    unsigned add = (tid < NBK && tid >= off) ? hist[tid - off] : 0u;
    __syncthreads();
    if (tid < NBK) hist[tid] += add;
    __syncthreads();
  }
  unsigned K = (unsigned)P.Kp[0];
  if (tid < NBK) {
    unsigned cum = hist[tid], prev = tid ? hist[tid - 1] : 0u;
    if (cum >= K && prev < K) {             // exactly one thread: tb = tid
      double S = sqrt(P.B1sq[b] * (double)cmax);
      // M: f16 input cvt + f32 accum + f16 STORE quantization (2x slack each)
      double M = 0.5 * S * 1.1e-3 + (50.0 + 0.55 * S) * 0x1p-10 + 0.05;
      double lot = lo + (double)tid * bw;
      sTL = (float)(lot - 2.0 * M - 1e-3);
      sTH = (float)(lot + bw + 2.0 * M + 1e-3);
    }
  }
  __syncthreads();
  float TL = sTL, TH = sTH;
  int shift = *P.shiftp;
  // ---- pass 2: classify (below -> lab, band -> candidate list) ----
  for (int i = tid; i < nu4; i += TPF) {
    uint4 u = rp4[i];
    unsigned uu[4] = {u.x, u.y, u.z, u.w};
#pragma unroll
    for (int k = 0; k < 8; ++k) {
      float v = h2f((unsigned short)((uu[k >> 1] >> ((k & 1) * 16)) & 0xFFFFu));
      if (v < TL) {
        atomicAdd(&lab[P.labels[(size_t)(i*8 + k) << shift]], 1u);
      } else if (v <= TH) {
        unsigned pos = atomicAdd(&cnt_s, 1u);
        if (pos < CAPC) kidx[pos] = i*8 + k;
      }
    }
  }
  for (int n = (nu4 << 3) + tid; n < P.N; n += TPF) {
    float v = h2f(rp[n]);
    if (v < TL) {
      atomicAdd(&lab[P.labels[(size_t)n << shift]], 1u);
    } else if (v <= TH) {
      unsigned pos = atomicAdd(&cnt_s, 1u);
      if (pos < CAPC) kidx[pos] = n;
    }
  }
  __syncthreads();
  // ---- btot, exact f64 keys, bitonic sort ----
  scr[tid] = 0.0f;                          // reuse scr as btot accumulator slots
  __syncthreads();
  unsigned bt = 0;
  for (int i = tid; i < NCLS; i += TPF) bt += lab[i];
  scr[tid] = (float)bt; __syncthreads();
  for (int off = TPF / 2; off > 0; off >>= 1) {
    if (tid < off) scr[tid] += scr[tid + off];
    __syncthreads();
  }
  int btot = (int)scr[0];
  int cnt = (int)cnt_s; if (cnt > CAPC) cnt = CAPC;
  int need = (int)K - btot;
  int M2 = 1; while (M2 < cnt) M2 <<= 1;
  const double* od = P.out64 + (size_t)b * 64;
  for (int i = tid; i < M2; i += TPF) {
    if (i < cnt) {
      key[i] = fma(dot1(P.codes, kidx[i], od), -0.5, 50.0);
    } else { key[i] = __builtin_inf(); kidx[i] = 0x7FFFFFFF; }
  }
  __syncthreads();
  for (int size = 2; size <= M2; size <<= 1) {
    for (int stride = size >> 1; stride > 0; stride >>= 1) {
      for (int i = tid; i < M2; i += TPF) {
        int j = i ^ stride;
        if (j > i) {
          double ki = key[i], kj = key[j];
          int ii = kidx[i], ij = kidx[j];
          bool up = ((i & size) == 0);
          bool sw = up ? (kj < ki || (kj == ki && ij < ii))
                       : (kj > ki || (kj == ki && ij > ii));
          if (sw) { key[i] = kj; key[j] = ki; kidx[i] = ij; kidx[j] = ii; }
        }
      }
      __syncthreads();
    }
  }
  // ---- take the quota into lab (lab already holds below counts), emit ----
  int take = need < cnt ? need : cnt;
  if (take < 0) take = 0;
  for (int i = tid; i < take; i += TPF)
    atomicAdd(&lab[P.labels[(size_t)kidx[i] << shift]], 1u);
  __syncthreads();
  double Kd = (double)K;
  for (int c = tid; c < NCLS; c += TPF)
    P.outp[b * NCLS + c] = (float)((double)lab[c] / Kd);
}

extern "C" void kernel_launch(void* const* d_in, const int* in_sizes, int n_in,
                              void* d_out, int out_size, void* d_ws, size_t ws_size,
                              hipStream_t stream) {
  Ptrs P;
  P.x      = (const float*)d_in[0];
  P.W      = (const float*)d_in[1];
  P.codes  = (const float*)d_in[2];
  P.labels = (const int*)d_in[3];
  P.Kp     = (const int*)d_in[4];
  P.B    = out_size / NCLS;                 // 256
  P.N    = in_sizes[3];                     // 100000
  P.D    = in_sizes[0] / P.B;               // 2048
  P.Npad = (P.N + 255) & ~255;              // 100096
  P.nCvt = P.Npad / 256;                    // 391
  P.gridPrep = P.nCvt + P.B + 1;            // cvt + out-rows + detect = 648
  P.cpb  = (((P.Npad + NCHX - 1) / NCHX) + 63) & ~63;  // 832
  P.outp = (float*)d_out;

  char* p = (char*)d_ws;
  P.out64    = (double*)p;         p += (size_t)P.B * 64 * sizeof(double);        // 128 KB
  P.out16    = (unsigned short*)p; p += (size_t)P.B * 64 * 2;                     // 32 KB
  P.B1sq     = (double*)p;         p += (size_t)P.B * sizeof(double);             // 2 KB
  P.shiftp   = (int*)p;            p += 64;
  P.pmax     = (float*)p;          p += 4096;                                     // 4 KB
  P.codes16  = (unsigned short*)p; p += (size_t)P.Npad * 64 * 2;                  // 12.8 MB
  P.simh     = (unsigned short*)p;                                                // 51.2 MB

  k_prep<<<P.gridPrep, TPB, 0, stream>>>(P);
  k_sim<<<dim3(NCHX, P.B / MROWS), TPB, 0, stream>>>(P);
  k_rowall<<<P.B, TPF, 0, stream>>>(P);
}